// Round 4
// baseline (2262.636 us; speedup 1.0000x reference)
//
#include <hip/hip_runtime.h>
#include <hip/hip_fp16.h>

#define HH 384
#define WW 384
#define HWSZ (HH*WW)   // 147456
#define NB 4

// ---- workspace layout ----
// h2 (fp16): [4][64][384][384] ushort = 75,497,472 B at offset 0
// weights (f32), float offsets from ws base:
static const size_t WT_F  = 18874368;          // = 75497472/4
static const size_t W1T_F = WT_F;              // [36][64]   2304 f
static const size_t W2T_F = WT_F + 2304;       // [576][64]  36864 f
static const size_t W3T_F = WT_F + 2304 + 36864; // [576][96] 55296 f (co pad 81->96, zeros)
// total ws usage: 75,875,328 B ~= 72.4 MiB (proven safe in R2/R3)

__device__ __forceinline__ float hl(unsigned u) {
  return (float)__ushort_as_half((unsigned short)(u & 0xffffu));
}
__device__ __forceinline__ float hh(unsigned u) {
  return (float)__ushort_as_half((unsigned short)(u >> 16));
}
__device__ __forceinline__ unsigned f2h(float f) {
  return (unsigned)__half_as_ushort(__float2half_rn(f));
}

// ---- prep: transpose weights to [ci*9+tap][co] (tiny, 94464 elements) ----
__global__ __launch_bounds__(256) void prep(const float* __restrict__ w1,
    const float* __restrict__ w2, const float* __restrict__ w3,
    float* __restrict__ ws) {
  int i = blockIdx.x * 256 + threadIdx.x;
  if (i < 2304)  { int co = i & 63, row = i >> 6; ws[W1T_F + i] = w1[co * 36 + row]; return; }
  int j = i - 2304;
  if (j < 36864) { int co = j & 63, row = j >> 6; ws[W2T_F + j] = w2[co * 576 + row]; return; }
  int j3 = j - 36864;
  if (j3 < 55296){ int co = j3 % 96, row = j3 / 96; ws[W3T_F + j3] = (co < 81) ? w3[co * 576 + row] : 0.f; }
}

// ---- stage 1: fused conv1+conv2 -> h2 (fp16) ----
// block 256 = 4 waves; wave = 16 co group; lane = (row, x-quad) of 16x16 tile.
__global__ __launch_bounds__(256, 3) void conv12(
    const float* __restrict__ rgb, const float* __restrict__ depth,
    const float* __restrict__ w1T, const float* __restrict__ w2T,
    const float* __restrict__ b1, const float* __restrict__ b2,
    unsigned short* __restrict__ h2) {
  __shared__ __align__(16) float xw[1600];        // x tile [4][20][20] f32
  __shared__ __align__(16) unsigned h1u[11520];   // h1 tile [64][18][20] fp16 (uint pairs)
  const int t = threadIdx.x;
  const int x0 = blockIdx.x * 16, y0 = blockIdx.y * 16, b = blockIdx.z;

  // phase A: stage input tile 20x20x4 (zero-padded), origin (-2,-2)
  for (int idx = t; idx < 1600; idx += 256) {
    int ci = idx / 400, r2 = idx % 400;
    int iy = r2 / 20, ix = r2 % 20;
    int gy = y0 + iy - 2, gx = x0 + ix - 2;
    float v = 0.f;
    if (gy >= 0 && gy < HH && gx >= 0 && gx < WW)
      v = (ci < 3) ? rgb[(size_t)(b * 3 + ci) * HWSZ + gy * WW + gx]
                   : depth[(size_t)b * HWSZ + gy * WW + gx];
    xw[idx] = v;
  }
  __syncthreads();

  // phase B: conv1 on 18x18 region -> h1 LDS (fp16). 162 items = 18 rows x 9 col-pairs.
  // CRITICAL: h1 halo positions OUTSIDE the image must be ZERO (conv2 SAME-pads h1
  // with zeros); conv1 evaluated at y=-1/384 etc. is nonzero and WRONG there.
  if (t < 162) {
    const int row = t / 9, cp = t % 9, c0 = cp * 2;
    const int gy1 = y0 + row - 1;
    const bool okY = (unsigned)gy1 < (unsigned)HH;
    const bool ok0 = okY && ((unsigned)(x0 + c0 - 1) < (unsigned)WW);
    const bool ok1 = okY && ((unsigned)(x0 + c0)     < (unsigned)WW);
    for (int cog = 0; cog < 4; ++cog) {
      const int co0 = cog * 16;
      float acc[2][16];
      #pragma unroll
      for (int k = 0; k < 16; ++k) { float bv = b1[co0 + k]; acc[0][k] = bv; acc[1][k] = bv; }
      #pragma unroll
      for (int ci = 0; ci < 4; ++ci) {
        #pragma unroll
        for (int ky = 0; ky < 3; ++ky) {
          int base = ci * 400 + (row + ky) * 20 + c0;
          float2 xa = *(const float2*)&xw[base];
          float2 xb = *(const float2*)&xw[base + 2];
          float xv[4] = {xa.x, xa.y, xb.x, xb.y};
          #pragma unroll
          for (int kx = 0; kx < 3; ++kx) {
            const float* wr = w1T + (ci * 9 + ky * 3 + kx) * 64 + co0;  // uniform -> s_load
            #pragma unroll
            for (int k = 0; k < 16; ++k) {
              float w = wr[k];
              acc[0][k] = fmaf(xv[kx], w, acc[0][k]);
              acc[1][k] = fmaf(xv[kx + 1], w, acc[1][k]);
            }
          }
        }
      }
      #pragma unroll
      for (int k = 0; k < 16; ++k) {
        unsigned lo = ok0 ? f2h(fmaxf(acc[0][k], 0.f)) : 0u;
        unsigned hi = ok1 ? f2h(fmaxf(acc[1][k], 0.f)) : 0u;
        h1u[(co0 + k) * 180 + row * 10 + cp] = lo | (hi << 16);
      }
    }
  }
  __syncthreads();

  // phase C: conv2 16x16x64 from h1 LDS; weights via wave-uniform scalar loads.
  const int lane = t & 63;
  const int r = lane >> 2, qc = lane & 3;
  const int co0 = __builtin_amdgcn_readfirstlane((t >> 6) * 16);
  float acc[4][16];
  #pragma unroll
  for (int k = 0; k < 16; ++k) {
    float bv = b2[co0 + k];
    #pragma unroll
    for (int j = 0; j < 4; ++j) acc[j][k] = bv;
  }
  #pragma unroll 1
  for (int c1 = 0; c1 < 64; ++c1) {
    #pragma unroll
    for (int ky = 0; ky < 3; ++ky) {
      int ui = c1 * 180 + (r + ky) * 10 + qc * 2;
      uint2 q = *(const uint2*)&h1u[ui];
      unsigned q2 = h1u[ui + 2];
      float v[6] = {hl(q.x), hh(q.x), hl(q.y), hh(q.y), hl(q2), hh(q2)};
      #pragma unroll
      for (int kx = 0; kx < 3; ++kx) {
        const float* wr = w2T + (c1 * 9 + ky * 3 + kx) * 64 + co0;  // uniform -> s_load
        #pragma unroll
        for (int k = 0; k < 16; ++k) {
          float w = wr[k];
          #pragma unroll
          for (int j = 0; j < 4; ++j) acc[j][k] = fmaf(v[kx + j], w, acc[j][k]);
        }
      }
    }
  }
  // store h2 (relu, fp16, 4 px packed as uint2)
  const int gy = y0 + r, gx = x0 + qc * 4;
  #pragma unroll
  for (int k = 0; k < 16; ++k) {
    unsigned u0 = f2h(fmaxf(acc[0][k], 0.f));
    unsigned u1 = f2h(fmaxf(acc[1][k], 0.f));
    unsigned u2 = f2h(fmaxf(acc[2][k], 0.f));
    unsigned u3 = f2h(fmaxf(acc[3][k], 0.f));
    size_t o = (size_t)(b * 64 + co0 + k) * HWSZ + gy * WW + gx;
    *(uint2*)&h2[o] = make_uint2(u0 | (u1 << 16), u2 | (u3 << 16));
  }
}

// ---- stage 2: fused conv3 + softmax + bokeh ----
// block 384 = 6 waves; wave = 16-co group (co padded 81->96); lane = (row, x-quad).
__global__ __launch_bounds__(384, 3) void conv3bokeh(
    const unsigned short* __restrict__ h2, const float* __restrict__ rgb,
    const float* __restrict__ w3T, const float* __restrict__ b3,
    float* __restrict__ out) {
  __shared__ __align__(16) unsigned char smem[46080];
  unsigned* h2u       = (unsigned*)smem;            // h2 tile [64][18][20] fp16
  unsigned short* h2s = (unsigned short*)smem;
  float* rgbl = (float*)smem;                       // [3][24][24] f32   (after conv3)
  float* maxb = (float*)(smem + 6912);              // [256][6]
  float* part = (float*)(smem + 13056);             // [256][6][4]
  const int t = threadIdx.x;
  const int x0 = blockIdx.x * 16, y0 = blockIdx.y * 16, b = blockIdx.z;

  // stage h2 tile 18x18x64 (zero-padded outside image -> correct conv3 SAME pad)
  for (int idx = t; idx < 64 * 324; idx += 384) {
    int c = idx / 324, r2 = idx % 324;
    int iy = r2 / 18, ix = r2 % 18;
    int gy = y0 + iy - 1, gx = x0 + ix - 1;
    unsigned short v = 0;
    if (gy >= 0 && gy < HH && gx >= 0 && gx < WW)
      v = h2[(size_t)(b * 64 + c) * HWSZ + gy * WW + gx];
    h2s[c * 360 + iy * 20 + ix] = v;
  }
  __syncthreads();

  const int lane = t & 63;
  const int r = lane >> 2, qc = lane & 3;
  const int cg = t >> 6;
  const int co0 = __builtin_amdgcn_readfirstlane(cg * 16);
  float acc[4][16];
  #pragma unroll
  for (int k = 0; k < 16; ++k) {
    float bv = (co0 + k < 81) ? b3[co0 + k] : 0.f;
    #pragma unroll
    for (int j = 0; j < 4; ++j) acc[j][k] = bv;
  }
  #pragma unroll 1
  for (int c1 = 0; c1 < 64; ++c1) {
    #pragma unroll
    for (int ky = 0; ky < 3; ++ky) {
      int ui = c1 * 180 + (r + ky) * 10 + qc * 2;
      uint2 q = *(const uint2*)&h2u[ui];
      unsigned q2 = h2u[ui + 2];
      float v[6] = {hl(q.x), hh(q.x), hl(q.y), hh(q.y), hl(q2), hh(q2)};
      #pragma unroll
      for (int kx = 0; kx < 3; ++kx) {
        const float* wr = w3T + (c1 * 9 + ky * 3 + kx) * 96 + co0;  // uniform -> s_load
        #pragma unroll
        for (int k = 0; k < 16; ++k) {
          float w = wr[k];
          #pragma unroll
          for (int j = 0; j < 4; ++j) acc[j][k] = fmaf(v[kx + j], w, acc[j][k]);
        }
      }
    }
  }
  __syncthreads();   // h2 tile dead; LDS reused below

  // stage rgb tile [3][24][24] (origin -4) + write per-wave maxes
  for (int idx = t; idx < 1728; idx += 384) {
    int c = idx / 576, r2 = idx % 576;
    int ry = r2 / 24, rx = r2 % 24;
    int gy = y0 + ry - 4, gx = x0 + rx - 4;
    float v = 0.f;
    if (gy >= 0 && gy < HH && gx >= 0 && gx < WW)
      v = rgb[(size_t)(b * 3 + c) * HWSZ + gy * WW + gx];
    rgbl[c * 576 + ry * 24 + rx] = v;
  }
  #pragma unroll
  for (int j = 0; j < 4; ++j) {
    float m = -1e30f;
    #pragma unroll
    for (int k = 0; k < 16; ++k)
      if (co0 + k < 81) m = fmaxf(m, acc[j][k]);
    maxb[(r * 16 + qc * 4 + j) * 6 + cg] = m;
  }
  __syncthreads();

  // unnormalized partial sums per wave: (s, a0, a1, a2)
  #pragma unroll
  for (int j = 0; j < 4; ++j) {
    const int px = r * 16 + qc * 4 + j;
    float m = -1e30f;
    #pragma unroll
    for (int w = 0; w < 6; ++w) m = fmaxf(m, maxb[px * 6 + w]);
    float s = 0.f, a0 = 0.f, a1 = 0.f, a2 = 0.f;
    #pragma unroll
    for (int k = 0; k < 16; ++k) {
      if (co0 + k < 81) {
        int tap = co0 + k, ty = tap / 9, tx = tap - ty * 9;
        float e = __expf(acc[j][k] - m);
        s += e;                                    // denominator over ALL 81 taps
        int ry = r + ty, rx = qc * 4 + j + tx;     // rgbl zero-padded -> OOB taps add 0
        a0 = fmaf(e, rgbl[ry * 24 + rx], a0);
        a1 = fmaf(e, rgbl[576 + ry * 24 + rx], a1);
        a2 = fmaf(e, rgbl[1152 + ry * 24 + rx], a2);
      }
    }
    *(float4*)&part[px * 24 + cg * 4] = make_float4(s, a0, a1, a2);
  }
  __syncthreads();

  // final cross-wave reduce + store
  if (t < 256) {
    const int px = t, rr = px >> 4, cx = px & 15;
    float s = 0.f, a0 = 0.f, a1 = 0.f, a2 = 0.f;
    #pragma unroll
    for (int w = 0; w < 6; ++w) {
      float4 p = *(const float4*)&part[px * 24 + w * 4];
      s += p.x; a0 += p.y; a1 += p.z; a2 += p.w;
    }
    float inv = 1.f / s;
    size_t o = (size_t)b * 3 * HWSZ + (size_t)(y0 + rr) * WW + (x0 + cx);
    out[o] = a0 * inv;
    out[o + HWSZ] = a1 * inv;
    out[o + 2 * HWSZ] = a2 * inv;
  }
}

extern "C" void kernel_launch(void* const* d_in, const int* in_sizes, int n_in,
                              void* d_out, int out_size, void* d_ws, size_t ws_size,
                              hipStream_t stream) {
  const float* rgb   = (const float*)d_in[0];
  const float* depth = (const float*)d_in[1];
  const float* w1    = (const float*)d_in[2];
  const float* b1    = (const float*)d_in[3];
  const float* w2    = (const float*)d_in[4];
  const float* b2    = (const float*)d_in[5];
  const float* w3    = (const float*)d_in[6];
  const float* b3    = (const float*)d_in[7];
  float* wsf = (float*)d_ws;
  unsigned short* h2 = (unsigned short*)d_ws;
  float* out = (float*)d_out;

  prep<<<369, 256, 0, stream>>>(w1, w2, w3, wsf);

  dim3 grid(WW / 16, HH / 16, NB);  // 24 x 24 x 4
  conv12<<<grid, 256, 0, stream>>>(rgb, depth, wsf + W1T_F, wsf + W2T_F, b1, b2, h2);
  conv3bokeh<<<grid, 384, 0, stream>>>(h2, rgb, wsf + W3T_F, b3, out);
}

// Round 5
// 661.841 us; speedup vs baseline: 3.4187x; 3.4187x over previous
//
#include <hip/hip_runtime.h>
#include <hip/hip_fp16.h>

#define HH 384
#define WW 384
#define HWSZ (HH*WW)   // 147456
#define NB 4

typedef _Float16 f16x8 __attribute__((ext_vector_type(8)));
typedef float    f32x4 __attribute__((ext_vector_type(4)));

// ---- ws layout (bytes) ----
// h2 fp16 NCHW [4][64][384][384]: 75,497,472 B @ 0
#define W1T_B 75497472u               // [36][64] f32, 9216 B
#define W2F_B (W1T_B + 9216u)         // [2][9][4][64][8] f16, 73728 B  (B-frag order)
#define W3F_B (W2F_B + 73728u)        // [2][9][6][64][8] f16, 110592 B (B-frag order, co pad 96)
// total 75,691,008 B ~= 72.2 MiB (R4 proved ~72.4 MiB is safe)

// ---- prep: w1 transpose (f32) + w2/w3 packed into MFMA B-fragment order (f16) ----
// B-frag for 16x16x32: lane l supplies B[k=(l>>4)*8+j][n=l&15]; frag = 64 lanes x 8 halfs.
__global__ __launch_bounds__(256) void prep(const float* __restrict__ w1,
    const float* __restrict__ w2, const float* __restrict__ w3, char* __restrict__ ws) {
  int i = blockIdx.x * 256 + threadIdx.x;
  float* w1T = (float*)(ws + W1T_B);
  _Float16* w2f = (_Float16*)(ws + W2F_B);
  _Float16* w3f = (_Float16*)(ws + W3F_B);
  if (i < 2304) { int co = i & 63, row = i >> 6; w1T[i] = w1[co * 36 + row]; return; }
  int o = i - 2304;
  if (o < 36864) {  // w2f: [cc][tap][cj][lane][j] strides 18432/2048/512/8/1
    int cc = o / 18432, rem = o % 18432;
    int tap = rem >> 11, r2 = rem & 2047;
    int cj = r2 >> 9, l = (r2 >> 3) & 63, j = r2 & 7;
    int co = cj * 16 + (l & 15);
    int ci = cc * 32 + (l >> 4) * 8 + j;
    w2f[o] = (_Float16)w2[co * 576 + ci * 9 + tap];
    return;
  }
  o -= 36864;
  if (o < 55296) {  // w3f: [cc][tap][cj][lane][j] strides 27648/3072/512/8/1
    int cc = o / 27648, rem = o % 27648;
    int tap = rem / 3072, r2 = rem % 3072;
    int cj = r2 >> 9, l = (r2 >> 3) & 63, j = r2 & 7;
    int co = cj * 16 + (l & 15);
    int ci = cc * 32 + (l >> 4) * 8 + j;
    w3f[o] = (co < 81) ? (_Float16)w3[co * 576 + ci * 9 + tap] : (_Float16)0.f;
  }
}

// ---- stage 1: fused conv1 (VALU) + conv2 (MFMA) -> h2 fp16 NCHW ----
// block = 16x16 px, 256 thr = 4 waves; wave w owns output rows w*4..w*4+3, all 64 co.
__global__ __launch_bounds__(256) void conv12(
    const float* __restrict__ rgb, const float* __restrict__ depth,
    const float* __restrict__ b1, const float* __restrict__ b2,
    const char* __restrict__ wsro, unsigned short* __restrict__ h2) {
  __shared__ _Float16 h1T[18 * 18 * 32];   // 20736 B  [row][col][ci32 swizzled]
  __shared__ float    xw[4 * 20 * 20];     // 6400 B   [ci][iy][ix] origin (-2,-2)
  __shared__ _Float16 w2l[9 * 4 * 512];    // 36864 B  [tap][cj][lane*8]
  const int t = threadIdx.x;
  const int x0 = blockIdx.x * 16, y0 = blockIdx.y * 16, b = blockIdx.z;
  const float* w1T = (const float*)(wsro + W1T_B);
  const _Float16* w2f = (const _Float16*)(wsro + W2F_B);
  const int lane = t & 63, q = lane >> 4, n = lane & 15, w = t >> 6;

  // stage input tile
  for (int idx = t; idx < 1600; idx += 256) {
    int ci = idx / 400, r2 = idx % 400, iy = r2 / 20, ix = r2 % 20;
    int gy = y0 + iy - 2, gx = x0 + ix - 2;
    float v = 0.f;
    if ((unsigned)gy < (unsigned)HH && (unsigned)gx < (unsigned)WW)
      v = (ci < 3) ? rgb[(size_t)(b * 3 + ci) * HWSZ + gy * WW + gx]
                   : depth[(size_t)b * HWSZ + gy * WW + gx];
    xw[idx] = v;
  }

  f32x4 acc[4][4];
  #pragma unroll
  for (int cj = 0; cj < 4; ++cj) {
    float bv = b2[cj * 16 + n];
    #pragma unroll
    for (int ri = 0; ri < 4; ++ri) acc[ri][cj] = (f32x4){bv, bv, bv, bv};
  }
  __syncthreads();

  for (int cc = 0; cc < 2; ++cc) {
    // stage w2 frag chunk (contiguous 36864 B)
    {
      const float4* src = (const float4*)(w2f + cc * 18432);
      float4* dst = (float4*)w2l;
      for (int idx = t; idx < 2304; idx += 256) dst[idx] = src[idx];
    }
    // conv1: compute h1 co-chunk [cc*32, cc*32+32) on the 18x18 halo region.
    // OOB positions MUST be zero (conv2 zero-pads h1).
    for (int idx = t; idx < 324; idx += 256) {
      int row = idx / 18, col = idx % 18;
      bool ok = ((unsigned)(y0 + row - 1) < (unsigned)HH) &&
                ((unsigned)(x0 + col - 1) < (unsigned)WW);
      float a1[32];
      #pragma unroll
      for (int k = 0; k < 32; ++k) a1[k] = b1[cc * 32 + k];
      #pragma unroll 1
      for (int ci = 0; ci < 4; ++ci) {
        #pragma unroll 1
        for (int ky = 0; ky < 3; ++ky) {
          const float* xp = &xw[ci * 400 + (row + ky) * 20 + col];
          float xv[3] = {xp[0], xp[1], xp[2]};
          #pragma unroll
          for (int kx = 0; kx < 3; ++kx) {
            const float* wr = w1T + (ci * 9 + ky * 3 + kx) * 64 + cc * 32;  // uniform
            #pragma unroll
            for (int k = 0; k < 32; ++k) a1[k] = fmaf(xv[kx], wr[k], a1[k]);
          }
        }
      }
      int base = (row * 18 + col) * 32, sw = col & 3;
      #pragma unroll
      for (int g = 0; g < 4; ++g) {
        f16x8 hv;
        #pragma unroll
        for (int j = 0; j < 8; ++j)
          hv[j] = ok ? (_Float16)fmaxf(a1[g * 8 + j], 0.f) : (_Float16)0.f;
        *(f16x8*)&h1T[base + ((g ^ sw) * 8)] = hv;
      }
    }
    __syncthreads();

    // conv2 MFMA: 9 taps x (4 B-reads + 4 A-reads -> 16 MFMA)
    #pragma unroll 1
    for (int tap = 0; tap < 9; ++tap) {
      int ty = tap / 3, tx = tap % 3;
      f16x8 bf[4];
      #pragma unroll
      for (int cj = 0; cj < 4; ++cj)
        bf[cj] = *(const f16x8*)&w2l[(tap * 4 + cj) * 512 + lane * 8];
      f16x8 af[4];
      #pragma unroll
      for (int ri = 0; ri < 4; ++ri) {
        int row = w * 4 + ri + ty;           // 0..17
        int col = n + tx;                    // A-frag m = lane&15
        af[ri] = *(const f16x8*)&h1T[(row * 18 + col) * 32 + ((q ^ (col & 3)) * 8)];
      }
      #pragma unroll
      for (int ri = 0; ri < 4; ++ri)
        #pragma unroll
        for (int cj = 0; cj < 4; ++cj)
          acc[ri][cj] = __builtin_amdgcn_mfma_f32_16x16x32_f16(af[ri], bf[cj], acc[ri][cj], 0, 0, 0);
    }
    __syncthreads();
  }

  // epilogue: D layout row(m=x-off)=(lane>>4)*4+i, col(co)=lane&15. ReLU + fp16 pack.
  #pragma unroll
  for (int ri = 0; ri < 4; ++ri) {
    int y = y0 + w * 4 + ri;
    #pragma unroll
    for (int cj = 0; cj < 4; ++cj) {
      int co = cj * 16 + n;
      union { _Float16 h[4]; uint2 u; } p;
      #pragma unroll
      for (int i = 0; i < 4; ++i) p.h[i] = (_Float16)fmaxf(acc[ri][cj][i], 0.f);
      *(uint2*)&h2[(size_t)(b * 64 + co) * HWSZ + y * WW + x0 + q * 4] = p.u;
    }
  }
}

// ---- stage 2: conv3 (MFMA, co 81->96) + in-wave softmax + bokeh ----
__global__ __launch_bounds__(256) void conv3bokeh(
    const unsigned short* __restrict__ h2, const float* __restrict__ rgb,
    const float* __restrict__ b3, const char* __restrict__ wsro,
    float* __restrict__ out) {
  __shared__ _Float16 h2T[18 * 18 * 32];   // 20736 B  [row][col][ci32 swizzled]
  __shared__ float    rgbl[3 * 24 * 24];   // 6912 B   origin (-4,-4)
  __shared__ _Float16 w3l[3 * 6 * 512];    // 18432 B  [tt][cj][lane*8] (3-tap group)
  const int t = threadIdx.x;
  const int x0 = blockIdx.x * 16, y0 = blockIdx.y * 16, b = blockIdx.z;
  const _Float16* w3f = (const _Float16*)(wsro + W3F_B);
  const int lane = t & 63, q = lane >> 4, n = lane & 15, w = t >> 6;

  f32x4 acc[4][6];
  #pragma unroll
  for (int cj = 0; cj < 6; ++cj) {
    int tap = cj * 16 + n;
    float bv = (tap < 81) ? b3[tap] : 0.f;
    #pragma unroll
    for (int ri = 0; ri < 4; ++ri) acc[ri][cj] = (f32x4){bv, bv, bv, bv};
  }
  // stage rgb tile
  for (int idx = t; idx < 1728; idx += 256) {
    int c = idx / 576, r2 = idx % 576, ry = r2 / 24, rx = r2 % 24;
    int gy = y0 + ry - 4, gx = x0 + rx - 4;
    float v = 0.f;
    if ((unsigned)gy < (unsigned)HH && (unsigned)gx < (unsigned)WW)
      v = rgb[(size_t)(b * 3 + c) * HWSZ + gy * WW + gx];
    rgbl[idx] = v;
  }

  for (int cc = 0; cc < 2; ++cc) {
    // stage h2T chunk (transpose NCHW -> [row][col][ci], swizzled, zero-padded)
    for (int idx = t; idx < 576; idx += 256) {
      int ci = idx & 31, row = idx >> 5;
      int gy = y0 + row - 1;
      bool okY = (unsigned)gy < (unsigned)HH;
      const unsigned short* src =
          h2 + ((size_t)(b * 64 + cc * 32 + ci) * HWSZ + (size_t)gy * WW + x0 - 1);
      int g = ci >> 3, of = ci & 7;
      #pragma unroll 1
      for (int col = 0; col < 18; ++col) {
        unsigned short v = 0;
        if (okY && (unsigned)(x0 + col - 1) < (unsigned)WW) v = src[col];
        h2T[(row * 18 + col) * 32 + ((g ^ (col & 3)) * 8) + of] = *(_Float16*)&v;
      }
    }
    #pragma unroll 1
    for (int tg = 0; tg < 3; ++tg) {
      {
        const float4* src = (const float4*)(w3f + cc * 27648 + tg * 9216);
        float4* dst = (float4*)w3l;
        for (int idx = t; idx < 1152; idx += 256) dst[idx] = src[idx];
      }
      __syncthreads();
      #pragma unroll 1
      for (int tt = 0; tt < 3; ++tt) {
        int tap = tg * 3 + tt, ty = tap / 3, tx = tap % 3;
        f16x8 bf[6];
        #pragma unroll
        for (int cj = 0; cj < 6; ++cj)
          bf[cj] = *(const f16x8*)&w3l[(tt * 6 + cj) * 512 + lane * 8];
        f16x8 af[4];
        #pragma unroll
        for (int ri = 0; ri < 4; ++ri) {
          int row = w * 4 + ri + ty;
          int col = n + tx;
          af[ri] = *(const f16x8*)&h2T[(row * 18 + col) * 32 + ((q ^ (col & 3)) * 8)];
        }
        #pragma unroll
        for (int ri = 0; ri < 4; ++ri)
          #pragma unroll
          for (int cj = 0; cj < 6; ++cj)
            acc[ri][cj] = __builtin_amdgcn_mfma_f32_16x16x32_f16(af[ri], bf[cj], acc[ri][cj], 0, 0, 0);
      }
      __syncthreads();   // protects w3l (and h2T on last tg) before overwrite
    }
  }

  // epilogue: per-pixel softmax over 81 taps (lanes n=0..15 x cj=0..5) + bokeh gather.
  int tyj[6], txj[6]; float vm[6];
  #pragma unroll
  for (int cj = 0; cj < 6; ++cj) {
    int tap = cj * 16 + n;
    tyj[cj] = tap / 9; txj[cj] = tap % 9;
    vm[cj] = (tap < 81) ? 1.f : 0.f;
  }
  #pragma unroll 1
  for (int ri = 0; ri < 4; ++ri) {
    int ry0 = w * 4 + ri;
    float mx[4];
    #pragma unroll
    for (int i = 0; i < 4; ++i) {
      float m = -1e30f;
      #pragma unroll
      for (int cj = 0; cj < 6; ++cj)
        m = fmaxf(m, vm[cj] > 0.f ? acc[ri][cj][i] : -1e30f);
      mx[i] = m;
    }
    #pragma unroll
    for (int st = 1; st < 16; st <<= 1)
      #pragma unroll
      for (int i = 0; i < 4; ++i) mx[i] = fmaxf(mx[i], __shfl_xor(mx[i], st));
    float s[4] = {0, 0, 0, 0}, a0[4] = {0, 0, 0, 0}, a1[4] = {0, 0, 0, 0}, a2[4] = {0, 0, 0, 0};
    #pragma unroll
    for (int cj = 0; cj < 6; ++cj) {
      int ry = ry0 + tyj[cj];
      #pragma unroll
      for (int i = 0; i < 4; ++i) {
        float e = vm[cj] * __expf(acc[ri][cj][i] - mx[i]);
        s[i] += e;
        int rx = q * 4 + i + txj[cj];
        a0[i] = fmaf(e, rgbl[ry * 24 + rx], a0[i]);
        a1[i] = fmaf(e, rgbl[576 + ry * 24 + rx], a1[i]);
        a2[i] = fmaf(e, rgbl[1152 + ry * 24 + rx], a2[i]);
      }
    }
    #pragma unroll
    for (int st = 1; st < 16; st <<= 1)
      #pragma unroll
      for (int i = 0; i < 4; ++i) {
        s[i] += __shfl_xor(s[i], st);
        a0[i] += __shfl_xor(a0[i], st);
        a1[i] += __shfl_xor(a1[i], st);
        a2[i] += __shfl_xor(a2[i], st);
      }
    if (n == 0) {
      int y = y0 + ry0;
      #pragma unroll
      for (int i = 0; i < 4; ++i) {
        int x = x0 + q * 4 + i;
        float inv = 1.f / s[i];
        size_t o = (size_t)b * 3 * HWSZ + (size_t)y * WW + x;
        out[o] = a0[i] * inv;
        out[o + HWSZ] = a1[i] * inv;
        out[o + 2 * HWSZ] = a2[i] * inv;
      }
    }
  }
}

extern "C" void kernel_launch(void* const* d_in, const int* in_sizes, int n_in,
                              void* d_out, int out_size, void* d_ws, size_t ws_size,
                              hipStream_t stream) {
  const float* rgb   = (const float*)d_in[0];
  const float* depth = (const float*)d_in[1];
  const float* w1    = (const float*)d_in[2];
  const float* b1    = (const float*)d_in[3];
  const float* w2    = (const float*)d_in[4];
  const float* b2    = (const float*)d_in[5];
  const float* w3    = (const float*)d_in[6];
  const float* b3    = (const float*)d_in[7];
  char* ws = (char*)d_ws;
  unsigned short* h2 = (unsigned short*)d_ws;
  float* out = (float*)d_out;

  prep<<<369, 256, 0, stream>>>(w1, w2, w3, ws);

  dim3 grid(WW / 16, HH / 16, NB);  // 24 x 24 x 4
  conv12<<<grid, 256, 0, stream>>>(rgb, depth, b1, b2, ws, h2);
  conv3bokeh<<<grid, 256, 0, stream>>>(h2, rgb, b3, ws, out);
}

// Round 6
// 504.065 us; speedup vs baseline: 4.4888x; 1.3130x over previous
//
#include <hip/hip_runtime.h>
#include <hip/hip_fp16.h>

#define HH 384
#define WW 384
#define HWSZ (HH*WW)   // 147456
#define NB 4

typedef _Float16 f16x8 __attribute__((ext_vector_type(8)));
typedef float    f32x4 __attribute__((ext_vector_type(4)));

// ---- ws layout (bytes) ----
// h2 fp16 NHWC [4][384][384][64]: 75,497,472 B @ 0
#define W1T_B 75497472u               // [36][64] f32, 9216 B
#define W2F_B (W1T_B + 9216u)         // [2][9][4][64][8] f16, 73728 B  (B-frag order)
#define W3F_B (W2F_B + 73728u)        // [2][9][6][64][8] f16, 110592 B (B-frag order, co pad 96)
// total 75,691,008 B ~= 72.2 MiB (proven safe)

// ---- prep: w1 transpose (f32) + w2/w3 packed into MFMA B-fragment order (f16) ----
// B-frag for 16x16x32: lane l supplies B[k=(l>>4)*8+j][n=l&15]; frag = 64 lanes x 8 halfs.
__global__ __launch_bounds__(256) void prep(const float* __restrict__ w1,
    const float* __restrict__ w2, const float* __restrict__ w3, char* __restrict__ ws) {
  int i = blockIdx.x * 256 + threadIdx.x;
  float* w1T = (float*)(ws + W1T_B);
  _Float16* w2f = (_Float16*)(ws + W2F_B);
  _Float16* w3f = (_Float16*)(ws + W3F_B);
  if (i < 2304) { int co = i & 63, row = i >> 6; w1T[i] = w1[co * 36 + row]; return; }
  int o = i - 2304;
  if (o < 36864) {  // w2f: [cc][tap][cj][lane][j] strides 18432/2048/512/8/1
    int cc = o / 18432, rem = o % 18432;
    int tap = rem >> 11, r2 = rem & 2047;
    int cj = r2 >> 9, l = (r2 >> 3) & 63, j = r2 & 7;
    int co = cj * 16 + (l & 15);
    int ci = cc * 32 + (l >> 4) * 8 + j;
    w2f[o] = (_Float16)w2[co * 576 + ci * 9 + tap];
    return;
  }
  o -= 36864;
  if (o < 55296) {  // w3f: [cc][tap][cj][lane][j] strides 27648/3072/512/8/1
    int cc = o / 27648, rem = o % 27648;
    int tap = rem / 3072, r2 = rem % 3072;
    int cj = r2 >> 9, l = (r2 >> 3) & 63, j = r2 & 7;
    int co = cj * 16 + (l & 15);
    int ci = cc * 32 + (l >> 4) * 8 + j;
    w3f[o] = (co < 81) ? (_Float16)w3[co * 576 + ci * 9 + tap] : (_Float16)0.f;
  }
}

// ---- stage 1: fused conv1 (VALU) + conv2 (MFMA) -> h2 fp16 NHWC ----
// block = 16x16 px, 256 thr = 4 waves; wave w owns output rows w*4..w*4+3, all 64 co.
__global__ __launch_bounds__(256) void conv12(
    const float* __restrict__ rgb, const float* __restrict__ depth,
    const float* __restrict__ b1, const float* __restrict__ b2,
    const char* __restrict__ wsro, unsigned short* __restrict__ h2) {
  __shared__ __align__(16) char smem[64000];
  float*    xw  = (float*)smem;                 // 6400 B  [4][20][20] origin (-2,-2)
  _Float16* h1T = (_Float16*)(smem + 6400);     // 20736 B [18*18][32] swizzled
  _Float16* w2l = (_Float16*)(smem + 27136);    // 36864 B [tap][cj][lane*8]
  _Float16* tr  = (_Float16*)(smem + 27136);    // alias w2l: epilogue [16][16][72]
  const int t = threadIdx.x;
  const int x0 = blockIdx.x * 16, y0 = blockIdx.y * 16, b = blockIdx.z;
  const float* w1T = (const float*)(wsro + W1T_B);
  const _Float16* w2f = (const _Float16*)(wsro + W2F_B);
  const int lane = t & 63, q = lane >> 4, n = lane & 15, w = t >> 6;

  // stage input tile
  for (int idx = t; idx < 1600; idx += 256) {
    int ci = idx / 400, r2 = idx % 400, iy = r2 / 20, ix = r2 % 20;
    int gy = y0 + iy - 2, gx = x0 + ix - 2;
    float v = 0.f;
    if ((unsigned)gy < (unsigned)HH && (unsigned)gx < (unsigned)WW)
      v = (ci < 3) ? rgb[(size_t)(b * 3 + ci) * HWSZ + gy * WW + gx]
                   : depth[(size_t)b * HWSZ + gy * WW + gx];
    xw[idx] = v;
  }

  f32x4 acc[4][4];
  #pragma unroll
  for (int cj = 0; cj < 4; ++cj) {
    float bv = b2[cj * 16 + n];
    #pragma unroll
    for (int ri = 0; ri < 4; ++ri) acc[ri][cj] = (f32x4){bv, bv, bv, bv};
  }
  __syncthreads();

  for (int cc = 0; cc < 2; ++cc) {
    // stage w2 frag chunk (contiguous 36864 B)
    {
      const float4* src = (const float4*)(w2f + cc * 18432);
      float4* dst = (float4*)w2l;
      for (int idx = t; idx < 2304; idx += 256) dst[idx] = src[idx];
    }
    // conv1: compute h1 co-chunk [cc*32, cc*32+32) on the 18x18 halo region.
    // OOB positions MUST be zero (conv2 zero-pads h1).
    for (int idx = t; idx < 324; idx += 256) {
      int row = idx / 18, col = idx % 18;
      bool ok = ((unsigned)(y0 + row - 1) < (unsigned)HH) &&
                ((unsigned)(x0 + col - 1) < (unsigned)WW);
      float a1[32];
      #pragma unroll
      for (int k = 0; k < 32; ++k) a1[k] = b1[cc * 32 + k];
      #pragma unroll 1
      for (int ci = 0; ci < 4; ++ci) {
        #pragma unroll 1
        for (int ky = 0; ky < 3; ++ky) {
          const float* xp = &xw[ci * 400 + (row + ky) * 20 + col];
          float xv[3] = {xp[0], xp[1], xp[2]};
          #pragma unroll
          for (int kx = 0; kx < 3; ++kx) {
            const float* wr = w1T + (ci * 9 + ky * 3 + kx) * 64 + cc * 32;  // uniform
            #pragma unroll
            for (int k = 0; k < 32; ++k) a1[k] = fmaf(xv[kx], wr[k], a1[k]);
          }
        }
      }
      int base = (row * 18 + col) * 32, sw = col & 3;
      #pragma unroll
      for (int g = 0; g < 4; ++g) {
        f16x8 hv;
        #pragma unroll
        for (int j = 0; j < 8; ++j)
          hv[j] = ok ? (_Float16)fmaxf(a1[g * 8 + j], 0.f) : (_Float16)0.f;
        *(f16x8*)&h1T[base + ((g ^ sw) * 8)] = hv;
      }
    }
    __syncthreads();

    // conv2 MFMA: 9 taps x (4 B-reads + 4 A-reads -> 16 MFMA)
    #pragma unroll 1
    for (int tap = 0; tap < 9; ++tap) {
      int ty = tap / 3, tx = tap % 3;
      f16x8 bf[4];
      #pragma unroll
      for (int cj = 0; cj < 4; ++cj)
        bf[cj] = *(const f16x8*)&w2l[(tap * 4 + cj) * 512 + lane * 8];
      f16x8 af[4];
      #pragma unroll
      for (int ri = 0; ri < 4; ++ri) {
        int row = w * 4 + ri + ty;           // 0..17
        int col = n + tx;                    // A-frag m = lane&15 = x
        af[ri] = *(const f16x8*)&h1T[(row * 18 + col) * 32 + ((q ^ (col & 3)) * 8)];
      }
      #pragma unroll
      for (int ri = 0; ri < 4; ++ri)
        #pragma unroll
        for (int cj = 0; cj < 4; ++cj)
          acc[ri][cj] = __builtin_amdgcn_mfma_f32_16x16x32_f16(af[ri], bf[cj], acc[ri][cj], 0, 0, 0);
    }
    __syncthreads();
  }

  // epilogue: ReLU + fp16, transpose via LDS (tr aliases dead w2l), NHWC coalesced store.
  // D layout: x = q*4+i, co = cj*16+n, y = w*4+ri.
  #pragma unroll
  for (int ri = 0; ri < 4; ++ri) {
    int py = w * 4 + ri;
    #pragma unroll
    for (int cj = 0; cj < 4; ++cj)
      #pragma unroll
      for (int i = 0; i < 4; ++i)
        tr[(py * 16 + q * 4 + i) * 72 + cj * 16 + n] = (_Float16)fmaxf(acc[ri][cj][i], 0.f);
  }
  __syncthreads();
  #pragma unroll
  for (int k = 0; k < 8; ++k) {
    int idx = t + k * 256;                     // [0,2048): y | x | c8
    int y = idx >> 7, x = (idx >> 3) & 15, c8 = (idx & 7) * 8;
    f16x8 v = *(const f16x8*)&tr[(y * 16 + x) * 72 + c8];
    *(f16x8*)&h2[(((size_t)b * HH + y0 + y) * WW + x0 + x) * 64 + c8] = v;
  }
}

// ---- stage 2: conv3 (MFMA, co 81->96) + in-wave softmax + bokeh ----
// block = 16x16 px, 512 thr = 8 waves; wave w owns rows 2w..2w+1 (acc[2][6] = 48 VGPR).
__global__ __launch_bounds__(512, 2) void conv3bokeh(
    const unsigned short* __restrict__ h2, const float* __restrict__ rgb,
    const float* __restrict__ b3, const char* __restrict__ wsro,
    float* __restrict__ out) {
  __shared__ __align__(16) char smem[46080];
  _Float16* h2T  = (_Float16*)smem;             // 20736 B [18*18][32] swizzled
  _Float16* w3l  = (_Float16*)(smem + 20736);   // 18432 B [tt][cj][lane*8]
  float*    rgbl = (float*)(smem + 39168);      // 6912 B  [3][24][24] origin (-4,-4)
  const int t = threadIdx.x;
  const int x0 = blockIdx.x * 16, y0 = blockIdx.y * 16, b = blockIdx.z;
  const _Float16* w3f = (const _Float16*)(wsro + W3F_B);
  const int lane = t & 63, q = lane >> 4, n = lane & 15, w = t >> 6;

  f32x4 acc[2][6];
  #pragma unroll
  for (int cj = 0; cj < 6; ++cj) {
    int tap = cj * 16 + n;
    float bv = (tap < 81) ? b3[tap] : 0.f;
    acc[0][cj] = (f32x4){bv, bv, bv, bv};
    acc[1][cj] = (f32x4){bv, bv, bv, bv};
  }
  // stage rgb tile
  for (int idx = t; idx < 1728; idx += 512) {
    int c = idx / 576, r2 = idx % 576, ry = r2 / 24, rx = r2 % 24;
    int gy = y0 + ry - 4, gx = x0 + rx - 4;
    float v = 0.f;
    if ((unsigned)gy < (unsigned)HH && (unsigned)gx < (unsigned)WW)
      v = rgb[(size_t)(b * 3 + c) * HWSZ + gy * WW + gx];
    rgbl[idx] = v;
  }

  for (int cc = 0; cc < 2; ++cc) {
    // stage h2T chunk from NHWC h2: 16B-aligned coalesced f16x8 loads, zero-padded.
    for (int idx = t; idx < 1296; idx += 512) {
      int g = idx & 3, pc = idx >> 2;
      int row = pc / 18, col = pc % 18;
      int gy = y0 + row - 1, gx = x0 + col - 1;
      f16x8 v = {};
      if ((unsigned)gy < (unsigned)HH && (unsigned)gx < (unsigned)WW)
        v = *(const f16x8*)&h2[(((size_t)b * HH + gy) * WW + gx) * 64 + cc * 32 + g * 8];
      *(f16x8*)&h2T[(row * 18 + col) * 32 + ((g ^ (col & 3)) * 8)] = v;
    }
    #pragma unroll 1
    for (int tg = 0; tg < 3; ++tg) {
      {
        const float4* src = (const float4*)(w3f + cc * 27648 + tg * 9216);
        float4* dst = (float4*)w3l;
        for (int idx = t; idx < 1152; idx += 512) dst[idx] = src[idx];
      }
      __syncthreads();
      #pragma unroll 1
      for (int tt = 0; tt < 3; ++tt) {
        int tap = tg * 3 + tt, ty = tap / 3, tx = tap % 3;
        f16x8 bf[6];
        #pragma unroll
        for (int cj = 0; cj < 6; ++cj)
          bf[cj] = *(const f16x8*)&w3l[(tt * 6 + cj) * 512 + lane * 8];
        f16x8 af[2];
        #pragma unroll
        for (int ri = 0; ri < 2; ++ri) {
          int row = w * 2 + ri + ty;           // 0..17
          int col = n + tx;
          af[ri] = *(const f16x8*)&h2T[(row * 18 + col) * 32 + ((q ^ (col & 3)) * 8)];
        }
        #pragma unroll
        for (int ri = 0; ri < 2; ++ri)
          #pragma unroll
          for (int cj = 0; cj < 6; ++cj)
            acc[ri][cj] = __builtin_amdgcn_mfma_f32_16x16x32_f16(af[ri], bf[cj], acc[ri][cj], 0, 0, 0);
      }
      __syncthreads();   // protects w3l (and h2T on last tg) before overwrite
    }
  }

  // epilogue: per-pixel softmax over 81 taps (lanes n=0..15 x cj=0..5) + bokeh gather.
  int tyj[6], txj[6]; float vm[6];
  #pragma unroll
  for (int cj = 0; cj < 6; ++cj) {
    int tap = cj * 16 + n;
    tyj[cj] = tap / 9; txj[cj] = tap % 9;
    vm[cj] = (tap < 81) ? 1.f : 0.f;
  }
  #pragma unroll 1
  for (int ri = 0; ri < 2; ++ri) {
    int ry0 = w * 2 + ri;
    float mx[4];
    #pragma unroll
    for (int i = 0; i < 4; ++i) {
      float m = -1e30f;
      #pragma unroll
      for (int cj = 0; cj < 6; ++cj)
        m = fmaxf(m, vm[cj] > 0.f ? acc[ri][cj][i] : -1e30f);
      mx[i] = m;
    }
    #pragma unroll
    for (int st = 1; st < 16; st <<= 1)
      #pragma unroll
      for (int i = 0; i < 4; ++i) mx[i] = fmaxf(mx[i], __shfl_xor(mx[i], st));
    float s[4] = {0, 0, 0, 0}, a0[4] = {0, 0, 0, 0}, a1[4] = {0, 0, 0, 0}, a2[4] = {0, 0, 0, 0};
    #pragma unroll
    for (int cj = 0; cj < 6; ++cj) {
      int ry = ry0 + tyj[cj];
      #pragma unroll
      for (int i = 0; i < 4; ++i) {
        float e = vm[cj] * __expf(acc[ri][cj][i] - mx[i]);
        s[i] += e;
        int rx = q * 4 + i + txj[cj];
        a0[i] = fmaf(e, rgbl[ry * 24 + rx], a0[i]);
        a1[i] = fmaf(e, rgbl[576 + ry * 24 + rx], a1[i]);
        a2[i] = fmaf(e, rgbl[1152 + ry * 24 + rx], a2[i]);
      }
    }
    #pragma unroll
    for (int st = 1; st < 16; st <<= 1)
      #pragma unroll
      for (int i = 0; i < 4; ++i) {
        s[i] += __shfl_xor(s[i], st);
        a0[i] += __shfl_xor(a0[i], st);
        a1[i] += __shfl_xor(a1[i], st);
        a2[i] += __shfl_xor(a2[i], st);
      }
    if (n == 0) {
      int y = y0 + ry0;
      #pragma unroll
      for (int i = 0; i < 4; ++i) {
        int x = x0 + q * 4 + i;
        float inv = 1.f / s[i];
        size_t o = (size_t)b * 3 * HWSZ + (size_t)y * WW + x;
        out[o] = a0[i] * inv;
        out[o + HWSZ] = a1[i] * inv;
        out[o + 2 * HWSZ] = a2[i] * inv;
      }
    }
  }
}

extern "C" void kernel_launch(void* const* d_in, const int* in_sizes, int n_in,
                              void* d_out, int out_size, void* d_ws, size_t ws_size,
                              hipStream_t stream) {
  const float* rgb   = (const float*)d_in[0];
  const float* depth = (const float*)d_in[1];
  const float* w1    = (const float*)d_in[2];
  const float* b1    = (const float*)d_in[3];
  const float* w2    = (const float*)d_in[4];
  const float* b2    = (const float*)d_in[5];
  const float* w3    = (const float*)d_in[6];
  const float* b3    = (const float*)d_in[7];
  char* ws = (char*)d_ws;
  unsigned short* h2 = (unsigned short*)d_ws;
  float* out = (float*)d_out;

  prep<<<369, 256, 0, stream>>>(w1, w2, w3, ws);

  dim3 grid(WW / 16, HH / 16, NB);  // 24 x 24 x 4
  conv12<<<grid, 256, 0, stream>>>(rgb, depth, b1, b2, ws, h2);
  conv3bokeh<<<grid, 512, 0, stream>>>(h2, rgb, b3, ws, out);
}

// Round 7
// 308.834 us; speedup vs baseline: 7.3264x; 1.6322x over previous
//
#include <hip/hip_runtime.h>
#include <hip/hip_fp16.h>

#define HH 384
#define WW 384
#define HWSZ (HH*WW)   // 147456
#define NB 4

typedef _Float16 f16x8 __attribute__((ext_vector_type(8)));
typedef float    f32x4 __attribute__((ext_vector_type(4)));

// ---- ws layout (bytes) ----
// h2 fp16 NHWC [4][384][384][64]: 75,497,472 B @ 0
#define W1T_B 75497472u               // [36][64] f32, 9216 B
#define W2F_B (W1T_B + 9216u)         // [2][9][4][64][8] f16, 73728 B  (B-frag order)
#define W3F_B (W2F_B + 73728u)        // [2][9][6][64][8] f16, 110592 B (B-frag order, co pad 96)
// total 75,691,008 B ~= 72.2 MiB (proven safe)

// ---- prep: w1 transpose (f32) + w2/w3 packed into MFMA B-fragment order (f16) ----
// B-frag for 16x16x32: lane l supplies B[k=(l>>4)*8+j][n=l&15]; frag = 64 lanes x 8 halfs.
__global__ __launch_bounds__(256) void prep(const float* __restrict__ w1,
    const float* __restrict__ w2, const float* __restrict__ w3, char* __restrict__ ws) {
  int i = blockIdx.x * 256 + threadIdx.x;
  float* w1T = (float*)(ws + W1T_B);
  _Float16* w2f = (_Float16*)(ws + W2F_B);
  _Float16* w3f = (_Float16*)(ws + W3F_B);
  if (i < 2304) { int co = i & 63, row = i >> 6; w1T[i] = w1[co * 36 + row]; return; }
  int o = i - 2304;
  if (o < 36864) {  // w2f: [cc][tap][cj][lane][j] strides 18432/2048/512/8/1
    int cc = o / 18432, rem = o % 18432;
    int tap = rem >> 11, r2 = rem & 2047;
    int cj = r2 >> 9, l = (r2 >> 3) & 63, j = r2 & 7;
    int co = cj * 16 + (l & 15);
    int ci = cc * 32 + (l >> 4) * 8 + j;
    w2f[o] = (_Float16)w2[co * 576 + ci * 9 + tap];
    return;
  }
  o -= 36864;
  if (o < 55296) {  // w3f: [cc][tap][cj][lane][j] strides 27648/3072/512/8/1
    int cc = o / 27648, rem = o % 27648;
    int tap = rem / 3072, r2 = rem % 3072;
    int cj = r2 >> 9, l = (r2 >> 3) & 63, j = r2 & 7;
    int co = cj * 16 + (l & 15);
    int ci = cc * 32 + (l >> 4) * 8 + j;
    w3f[o] = (co < 81) ? (_Float16)w3[co * 576 + ci * 9 + tap] : (_Float16)0.f;
  }
}

// ---- stage 1: fused conv1 (VALU) + conv2 (MFMA) -> h2 fp16 NHWC ----
// block = 16x16 px, 256 thr = 4 waves; wave w owns output rows w*4..w*4+3, all 64 co.
__global__ __launch_bounds__(256) void conv12(
    const float* __restrict__ rgb, const float* __restrict__ depth,
    const float* __restrict__ b1, const float* __restrict__ b2,
    const char* __restrict__ wsro, unsigned short* __restrict__ h2) {
  __shared__ __align__(16) char smem[64000];
  float*    xw  = (float*)smem;                 // 6400 B  [4][20][20] origin (-2,-2)
  _Float16* h1T = (_Float16*)(smem + 6400);     // 20736 B [18*18][32] swizzled
  _Float16* w2l = (_Float16*)(smem + 27136);    // 36864 B [tap][cj][lane*8]
  _Float16* tr  = (_Float16*)(smem + 27136);    // alias w2l: epilogue [16][16][72]
  const int t = threadIdx.x;
  const int x0 = blockIdx.x * 16, y0 = blockIdx.y * 16, b = blockIdx.z;
  const float* w1T = (const float*)(wsro + W1T_B);
  const _Float16* w2f = (const _Float16*)(wsro + W2F_B);
  const int lane = t & 63, q = lane >> 4, n = lane & 15, w = t >> 6;

  // stage input tile
  for (int idx = t; idx < 1600; idx += 256) {
    int ci = idx / 400, r2 = idx % 400, iy = r2 / 20, ix = r2 % 20;
    int gy = y0 + iy - 2, gx = x0 + ix - 2;
    float v = 0.f;
    if ((unsigned)gy < (unsigned)HH && (unsigned)gx < (unsigned)WW)
      v = (ci < 3) ? rgb[(size_t)(b * 3 + ci) * HWSZ + gy * WW + gx]
                   : depth[(size_t)b * HWSZ + gy * WW + gx];
    xw[idx] = v;
  }

  f32x4 acc[4][4];
  #pragma unroll
  for (int cj = 0; cj < 4; ++cj) {
    float bv = b2[cj * 16 + n];
    #pragma unroll
    for (int ri = 0; ri < 4; ++ri) acc[ri][cj] = (f32x4){bv, bv, bv, bv};
  }
  __syncthreads();

  for (int cc = 0; cc < 2; ++cc) {
    // stage w2 frag chunk (contiguous 36864 B)
    {
      const float4* src = (const float4*)(w2f + cc * 18432);
      float4* dst = (float4*)w2l;
      for (int idx = t; idx < 2304; idx += 256) dst[idx] = src[idx];
    }
    // conv1: compute h1 co-chunk [cc*32, cc*32+32) on the 18x18 halo region.
    // OOB positions MUST be zero (conv2 zero-pads h1).
    for (int idx = t; idx < 324; idx += 256) {
      int row = idx / 18, col = idx % 18;
      bool ok = ((unsigned)(y0 + row - 1) < (unsigned)HH) &&
                ((unsigned)(x0 + col - 1) < (unsigned)WW);
      float a1[32];
      #pragma unroll
      for (int k = 0; k < 32; ++k) a1[k] = b1[cc * 32 + k];
      #pragma unroll 1
      for (int ci = 0; ci < 4; ++ci) {
        #pragma unroll 1
        for (int ky = 0; ky < 3; ++ky) {
          const float* xp = &xw[ci * 400 + (row + ky) * 20 + col];
          float xv[3] = {xp[0], xp[1], xp[2]};
          #pragma unroll
          for (int kx = 0; kx < 3; ++kx) {
            const float* wr = w1T + (ci * 9 + ky * 3 + kx) * 64 + cc * 32;  // uniform
            #pragma unroll
            for (int k = 0; k < 32; ++k) a1[k] = fmaf(xv[kx], wr[k], a1[k]);
          }
        }
      }
      int base = (row * 18 + col) * 32, sw = col & 3;
      #pragma unroll
      for (int g = 0; g < 4; ++g) {
        f16x8 hv;
        #pragma unroll
        for (int j = 0; j < 8; ++j)
          hv[j] = ok ? (_Float16)fmaxf(a1[g * 8 + j], 0.f) : (_Float16)0.f;
        *(f16x8*)&h1T[base + ((g ^ sw) * 8)] = hv;
      }
    }
    __syncthreads();

    // conv2 MFMA: 9 taps x (4 B-reads + 4 A-reads -> 16 MFMA)
    #pragma unroll 1
    for (int tap = 0; tap < 9; ++tap) {
      int ty = tap / 3, tx = tap % 3;
      f16x8 bf[4];
      #pragma unroll
      for (int cj = 0; cj < 4; ++cj)
        bf[cj] = *(const f16x8*)&w2l[(tap * 4 + cj) * 512 + lane * 8];
      f16x8 af[4];
      #pragma unroll
      for (int ri = 0; ri < 4; ++ri) {
        int row = w * 4 + ri + ty;           // 0..17
        int col = n + tx;                    // A-frag m = lane&15 = x
        af[ri] = *(const f16x8*)&h1T[(row * 18 + col) * 32 + ((q ^ (col & 3)) * 8)];
      }
      #pragma unroll
      for (int ri = 0; ri < 4; ++ri)
        #pragma unroll
        for (int cj = 0; cj < 4; ++cj)
          acc[ri][cj] = __builtin_amdgcn_mfma_f32_16x16x32_f16(af[ri], bf[cj], acc[ri][cj], 0, 0, 0);
    }
    __syncthreads();
  }

  // epilogue: ReLU + fp16, transpose via LDS (tr aliases dead w2l), NHWC coalesced store.
  // D layout: x = q*4+i, co = cj*16+n, y = w*4+ri.
  #pragma unroll
  for (int ri = 0; ri < 4; ++ri) {
    int py = w * 4 + ri;
    #pragma unroll
    for (int cj = 0; cj < 4; ++cj)
      #pragma unroll
      for (int i = 0; i < 4; ++i)
        tr[(py * 16 + q * 4 + i) * 72 + cj * 16 + n] = (_Float16)fmaxf(acc[ri][cj][i], 0.f);
  }
  __syncthreads();
  #pragma unroll
  for (int k = 0; k < 8; ++k) {
    int idx = t + k * 256;                     // [0,2048): y | x | c8
    int y = idx >> 7, x = (idx >> 3) & 15, c8 = (idx & 7) * 8;
    f16x8 v = *(const f16x8*)&tr[(y * 16 + x) * 72 + c8];
    *(f16x8*)&h2[(((size_t)b * HH + y0 + y) * WW + x0 + x) * 64 + c8] = v;
  }
}

// ---- stage 2: conv3 (MFMA, co 81->96) + in-wave softmax + bokeh ----
// block = 16x16 px, 512 thr = 8 waves; wave w owns rows 2w..2w+1 (acc[2][6] = 48 VGPR).
// NOTE: every loop touching acc[][] must be FULLY UNROLLED — a runtime index on
// acc demotes it to scratch (R6: 1.5 GB of scratch churn from `#pragma unroll 1`).
__global__ __launch_bounds__(512, 2) void conv3bokeh(
    const unsigned short* __restrict__ h2, const float* __restrict__ rgb,
    const float* __restrict__ b3, const char* __restrict__ wsro,
    float* __restrict__ out) {
  __shared__ __align__(16) char smem[46080];
  _Float16* h2T  = (_Float16*)smem;             // 20736 B [18*18][32] swizzled
  _Float16* w3l  = (_Float16*)(smem + 20736);   // 18432 B [tt][cj][lane*8]
  float*    rgbl = (float*)(smem + 39168);      // 6912 B  [3][24][24] origin (-4,-4)
  const int t = threadIdx.x;
  const int x0 = blockIdx.x * 16, y0 = blockIdx.y * 16, b = blockIdx.z;
  const _Float16* w3f = (const _Float16*)(wsro + W3F_B);
  const int lane = t & 63, q = lane >> 4, n = lane & 15, w = t >> 6;

  f32x4 acc[2][6];
  #pragma unroll
  for (int cj = 0; cj < 6; ++cj) {
    int tap = cj * 16 + n;
    float bv = (tap < 81) ? b3[tap] : 0.f;
    acc[0][cj] = (f32x4){bv, bv, bv, bv};
    acc[1][cj] = (f32x4){bv, bv, bv, bv};
  }
  // stage rgb tile
  for (int idx = t; idx < 1728; idx += 512) {
    int c = idx / 576, r2 = idx % 576, ry = r2 / 24, rx = r2 % 24;
    int gy = y0 + ry - 4, gx = x0 + rx - 4;
    float v = 0.f;
    if ((unsigned)gy < (unsigned)HH && (unsigned)gx < (unsigned)WW)
      v = rgb[(size_t)(b * 3 + c) * HWSZ + gy * WW + gx];
    rgbl[idx] = v;
  }

  for (int cc = 0; cc < 2; ++cc) {
    // stage h2T chunk from NHWC h2: 16B-aligned coalesced f16x8 loads, zero-padded.
    for (int idx = t; idx < 1296; idx += 512) {
      int g = idx & 3, pc = idx >> 2;
      int row = pc / 18, col = pc % 18;
      int gy = y0 + row - 1, gx = x0 + col - 1;
      f16x8 v = {};
      if ((unsigned)gy < (unsigned)HH && (unsigned)gx < (unsigned)WW)
        v = *(const f16x8*)&h2[(((size_t)b * HH + gy) * WW + gx) * 64 + cc * 32 + g * 8];
      *(f16x8*)&h2T[(row * 18 + col) * 32 + ((g ^ (col & 3)) * 8)] = v;
    }
    #pragma unroll 1
    for (int tg = 0; tg < 3; ++tg) {
      {
        const float4* src = (const float4*)(w3f + cc * 27648 + tg * 9216);
        float4* dst = (float4*)w3l;
        for (int idx = t; idx < 1152; idx += 512) dst[idx] = src[idx];
      }
      __syncthreads();
      #pragma unroll 1
      for (int tt = 0; tt < 3; ++tt) {
        int tap = tg * 3 + tt, ty = tap / 3, tx = tap % 3;
        f16x8 bf[6];
        #pragma unroll
        for (int cj = 0; cj < 6; ++cj)
          bf[cj] = *(const f16x8*)&w3l[(tt * 6 + cj) * 512 + lane * 8];
        f16x8 af[2];
        #pragma unroll
        for (int ri = 0; ri < 2; ++ri) {
          int row = w * 2 + ri + ty;           // 0..17
          int col = n + tx;
          af[ri] = *(const f16x8*)&h2T[(row * 18 + col) * 32 + ((q ^ (col & 3)) * 8)];
        }
        #pragma unroll
        for (int ri = 0; ri < 2; ++ri)
          #pragma unroll
          for (int cj = 0; cj < 6; ++cj)
            acc[ri][cj] = __builtin_amdgcn_mfma_f32_16x16x32_f16(af[ri], bf[cj], acc[ri][cj], 0, 0, 0);
      }
      __syncthreads();   // protects w3l (and h2T on last tg) before overwrite
    }
  }

  // epilogue: per-pixel softmax over 81 taps (lanes n=0..15 x cj=0..5) + bokeh gather.
  // FULLY unrolled over ri (see note above).
  int tyj[6], txj[6]; float vm[6];
  #pragma unroll
  for (int cj = 0; cj < 6; ++cj) {
    int tap = cj * 16 + n;
    tyj[cj] = tap / 9; txj[cj] = tap % 9;
    vm[cj] = (tap < 81) ? 1.f : 0.f;
  }
  #pragma unroll
  for (int ri = 0; ri < 2; ++ri) {
    int ry0 = w * 2 + ri;
    float mx[4];
    #pragma unroll
    for (int i = 0; i < 4; ++i) {
      float m = -1e30f;
      #pragma unroll
      for (int cj = 0; cj < 6; ++cj)
        m = fmaxf(m, vm[cj] > 0.f ? acc[ri][cj][i] : -1e30f);
      mx[i] = m;
    }
    #pragma unroll
    for (int st = 1; st < 16; st <<= 1)
      #pragma unroll
      for (int i = 0; i < 4; ++i) mx[i] = fmaxf(mx[i], __shfl_xor(mx[i], st));
    float s[4] = {0, 0, 0, 0}, a0[4] = {0, 0, 0, 0}, a1[4] = {0, 0, 0, 0}, a2[4] = {0, 0, 0, 0};
    #pragma unroll
    for (int cj = 0; cj < 6; ++cj) {
      int ry = ry0 + tyj[cj];
      #pragma unroll
      for (int i = 0; i < 4; ++i) {
        float e = vm[cj] * __expf(acc[ri][cj][i] - mx[i]);
        s[i] += e;
        int rx = q * 4 + i + txj[cj];
        a0[i] = fmaf(e, rgbl[ry * 24 + rx], a0[i]);
        a1[i] = fmaf(e, rgbl[576 + ry * 24 + rx], a1[i]);
        a2[i] = fmaf(e, rgbl[1152 + ry * 24 + rx], a2[i]);
      }
    }
    #pragma unroll
    for (int st = 1; st < 16; st <<= 1)
      #pragma unroll
      for (int i = 0; i < 4; ++i) {
        s[i] += __shfl_xor(s[i], st);
        a0[i] += __shfl_xor(a0[i], st);
        a1[i] += __shfl_xor(a1[i], st);
        a2[i] += __shfl_xor(a2[i], st);
      }
    if (n == 0) {
      int y = y0 + ry0;
      #pragma unroll
      for (int i = 0; i < 4; ++i) {
        int x = x0 + q * 4 + i;
        float inv = 1.f / s[i];
        size_t o = (size_t)b * 3 * HWSZ + (size_t)y * WW + x;
        out[o] = a0[i] * inv;
        out[o + HWSZ] = a1[i] * inv;
        out[o + 2 * HWSZ] = a2[i] * inv;
      }
    }
  }
}

extern "C" void kernel_launch(void* const* d_in, const int* in_sizes, int n_in,
                              void* d_out, int out_size, void* d_ws, size_t ws_size,
                              hipStream_t stream) {
  const float* rgb   = (const float*)d_in[0];
  const float* depth = (const float*)d_in[1];
  const float* w1    = (const float*)d_in[2];
  const float* b1    = (const float*)d_in[3];
  const float* w2    = (const float*)d_in[4];
  const float* b2    = (const float*)d_in[5];
  const float* w3    = (const float*)d_in[6];
  const float* b3    = (const float*)d_in[7];
  char* ws = (char*)d_ws;
  unsigned short* h2 = (unsigned short*)d_ws;
  float* out = (float*)d_out;

  prep<<<369, 256, 0, stream>>>(w1, w2, w3, ws);

  dim3 grid(WW / 16, HH / 16, NB);  // 24 x 24 x 4
  conv12<<<grid, 256, 0, stream>>>(rgb, depth, b1, b2, ws, h2);
  conv3bokeh<<<grid, 512, 0, stream>>>(h2, rgb, b3, ws, out);
}